// Round 6
// baseline (389.186 us; speedup 1.0000x reference)
//
#include <hip/hip_runtime.h>
#include <hip/hip_bf16.h>
#include <math.h>

#define EPS 1e-6f

constexpr int D   = 512;
constexpr int BM  = 256;
constexpr int BN  = 256;
constexpr int TPB = 4;     // output tiles per persistent block (along M of B)

typedef __attribute__((ext_vector_type(8))) short  short8;
typedef __attribute__((ext_vector_type(4))) float  floatx4;

__device__ inline unsigned short f2bf(float f) {
  union { __hip_bfloat16 h; unsigned short u; } cvt;
  cvt.h = __float2bfloat16(f);
  return cvt.u;
}

// ---------------- prep: fp32 -> bf16 (norm-folded) + ||x||^(-1/2) ----------
// If *nrmflag, rows are pre-scaled by ||row||^(-1/2) before the bf16 cast, so
// the GEMM needs no epilogue scaling: a'.b' = a.b / sqrt(|a||b|). (EPS in the
// reference shifts the denominator by ~4e-8 relative — far below tolerance.)
__global__ __launch_bounds__(256) void prep_kernel(
    const float* __restrict__ src, __hip_bfloat16* __restrict__ dst,
    float* __restrict__ isn, const int* __restrict__ nrmflag, int nrows) {
  const int lane = threadIdx.x & 63;
  const int row  = blockIdx.x * 4 + (threadIdx.x >> 6);
  if (row >= nrows) return;

  const float4* p4 = (const float4*)(src + (size_t)row * D);
  const float4 v1 = p4[lane];
  const float4 v2 = p4[lane + 64];

  float ss = v1.x * v1.x + v1.y * v1.y + v1.z * v1.z + v1.w * v1.w
           + v2.x * v2.x + v2.y * v2.y + v2.z * v2.z + v2.w * v2.w;
  #pragma unroll
  for (int o = 32; o > 0; o >>= 1) ss += __shfl_xor(ss, o);   // all lanes get ss

  const float s4 = rsqrtf(sqrtf(ss));        // ss^(-1/4) = ||row||^(-1/2)
  if (lane == 0) isn[row] = s4;              // kept for fallback path

  if (dst != nullptr) {
    const float s = (*nrmflag) ? s4 : 1.0f;
    ushort4 u1, u2;
    u1.x = f2bf(v1.x * s); u1.y = f2bf(v1.y * s);
    u1.z = f2bf(v1.z * s); u1.w = f2bf(v1.w * s);
    u2.x = f2bf(v2.x * s); u2.y = f2bf(v2.y * s);
    u2.z = f2bf(v2.z * s); u2.w = f2bf(v2.w * s);
    ushort4* drow = (ushort4*)(dst + (size_t)row * D);
    drow[lane]      = u1;
    drow[lane + 64] = u2;
  }
}

// ---------------- persistent 256x256 bf16 MFMA GEMM, C = A * B^T -----------
// 256 blocks (1/CU), each owns TPB=4 tiles (same A panel, consecutive B
// panels). The K-tile staging stream runs CONTINUOUSLY across tiles: a tile's
// last KTILE pair stages the NEXT tile's kt0/kt1; the epilogue overlaps those
// in-flight loads. ALL counted waits are VM8: "≤8 outstanding" with the 8
// newest being the just-issued stage guarantees every older op (loads AND
// epilogue stores) has retired — no reliance on cross-type vmcnt retirement
// order. LDS = 128 KiB (proven footprint), scalar-store epilogue (proven
// perf-neutral vs dwordx4 in R1/R3).

#define GLD(srcp, ldsoff_shorts)                                              \
  __builtin_amdgcn_global_load_lds(                                           \
      (const __attribute__((address_space(1))) void*)(srcp),                  \
      (__attribute__((address_space(3))) void*)(smem + (ldsoff_shorts)),      \
      16, 0, 0)

// one K-tile = A 256x64 + B 256x64 bf16 = 64 KiB, 8 load instrs per thread
#define STAGE(aP, bP, b)                                                      \
  do {                                                                        \
    GLD((aP) + soff,                   ((b) * 2 + 0) * 8192 + t * 8);         \
    GLD((aP) + soff + (size_t)64 * D,  ((b) * 2 + 0) * 8192 + (t + 512) * 8); \
    GLD((aP) + soff + (size_t)128 * D, ((b) * 2 + 1) * 8192 + t * 8);         \
    GLD((aP) + soff + (size_t)192 * D, ((b) * 2 + 1) * 8192 + (t + 512) * 8); \
    GLD((bP) + soff,                   32768 + ((b) * 2 + 0) * 8192 + t * 8); \
    GLD((bP) + soff + (size_t)64 * D,  32768 + ((b) * 2 + 0) * 8192 + (t + 512) * 8); \
    GLD((bP) + soff + (size_t)128 * D, 32768 + ((b) * 2 + 1) * 8192 + t * 8); \
    GLD((bP) + soff + (size_t)192 * D, 32768 + ((b) * 2 + 1) * 8192 + (t + 512) * 8); \
  } while (0)

#define RD(p, m, off) (*(const short8*)((p) + (m) * 2048 + rbyte + (off)))

#define MM2(mi, ni)                                                           \
  do {                                                                        \
    acc[mi][ni] = __builtin_amdgcn_mfma_f32_16x16x32_bf16(                    \
        aR[(mi) & 3][0], bR[ni][0], acc[mi][ni], 0, 0, 0);                    \
    acc[mi][ni] = __builtin_amdgcn_mfma_f32_16x16x32_bf16(                    \
        aR[(mi) & 3][1], bR[ni][1], acc[mi][ni], 0, 0, 0);                    \
  } while (0)

#define BAR   __builtin_amdgcn_s_barrier()
#define LGKM0 do { asm volatile("s_waitcnt lgkmcnt(0)" ::: "memory");         \
                   __builtin_amdgcn_sched_barrier(0); } while (0)
#define VM8   asm volatile("s_waitcnt vmcnt(8)" ::: "memory")
#define VM0   asm volatile("s_waitcnt vmcnt(0)" ::: "memory")
#define NOOP  do {} while (0)

#define KTILE(b, STAGE_STMT, WAITV)                                           \
  do {                                                                        \
    const char* pA_ = (const char*)smem + ((b) * 2 + wm) * 16384;             \
    const char* pB_ = (const char*)smem + 65536                               \
                      + ((b) * 2 + (wn >> 1)) * 16384 + (wn & 1) * 8192;      \
    /* p1: A m0-3 + B n0-1 */                                                 \
    aR[0][0] = RD(pA_, 0, off0); aR[0][1] = RD(pA_, 0, off1);                 \
    aR[1][0] = RD(pA_, 1, off0); aR[1][1] = RD(pA_, 1, off1);                 \
    aR[2][0] = RD(pA_, 2, off0); aR[2][1] = RD(pA_, 2, off1);                 \
    aR[3][0] = RD(pA_, 3, off0); aR[3][1] = RD(pA_, 3, off1);                 \
    bR[0][0] = RD(pB_, 0, off0); bR[0][1] = RD(pB_, 0, off1);                 \
    bR[1][0] = RD(pB_, 1, off0); bR[1][1] = RD(pB_, 1, off1);                 \
    BAR; LGKM0;                                                               \
    __builtin_amdgcn_s_setprio(1);                                            \
    MM2(0,0); MM2(1,0); MM2(2,0); MM2(3,0);                                   \
    MM2(0,1); MM2(1,1); MM2(2,1); MM2(3,1);                                   \
    __builtin_amdgcn_s_setprio(0);                                            \
    BAR;                                                                      \
    /* p2: B n2-3 */                                                          \
    bR[2][0] = RD(pB_, 2, off0); bR[2][1] = RD(pB_, 2, off1);                 \
    bR[3][0] = RD(pB_, 3, off0); bR[3][1] = RD(pB_, 3, off1);                 \
    BAR; LGKM0;                                                               \
    __builtin_amdgcn_s_setprio(1);                                            \
    MM2(0,2); MM2(1,2); MM2(2,2); MM2(3,2);                                   \
    MM2(0,3); MM2(1,3); MM2(2,3); MM2(3,3);                                   \
    __builtin_amdgcn_s_setprio(0);                                            \
    BAR;                                                                      \
    /* p3: A m4-7 */                                                          \
    aR[0][0] = RD(pA_, 4, off0); aR[0][1] = RD(pA_, 4, off1);                 \
    aR[1][0] = RD(pA_, 5, off0); aR[1][1] = RD(pA_, 5, off1);                 \
    aR[2][0] = RD(pA_, 6, off0); aR[2][1] = RD(pA_, 6, off1);                 \
    aR[3][0] = RD(pA_, 7, off0); aR[3][1] = RD(pA_, 7, off1);                 \
    BAR; LGKM0;                                                               \
    __builtin_amdgcn_s_setprio(1);                                            \
    MM2(4,2); MM2(5,2); MM2(6,2); MM2(7,2);                                   \
    MM2(4,3); MM2(5,3); MM2(6,3); MM2(7,3);                                   \
    __builtin_amdgcn_s_setprio(0);                                            \
    BAR;                                                                      \
    /* p4: stage (this buffer's reads are complete) */                        \
    STAGE_STMT;                                                               \
    BAR;                                                                      \
    __builtin_amdgcn_s_setprio(1);                                            \
    MM2(4,0); MM2(5,0); MM2(6,0); MM2(7,0);                                   \
    MM2(4,1); MM2(5,1); MM2(6,1); MM2(7,1);                                   \
    __builtin_amdgcn_s_setprio(0);                                            \
    WAITV;                                                                    \
    BAR;                                                                      \
  } while (0)

// 8 KTILEs of one output tile; last pair runs LASTP (stage next tile / drain)
#define TILE8(bBp, LASTP0, LASTP1, WV0, WV1)                                  \
  do {                                                                        \
    KTILE(0, STAGE(gA + 128, (bBp) + 128, 0), VM8);                           \
    KTILE(1, STAGE(gA + 192, (bBp) + 192, 1), VM8);                           \
    KTILE(0, STAGE(gA + 256, (bBp) + 256, 0), VM8);                           \
    KTILE(1, STAGE(gA + 320, (bBp) + 320, 1), VM8);                           \
    KTILE(0, STAGE(gA + 384, (bBp) + 384, 0), VM8);                           \
    KTILE(1, STAGE(gA + 448, (bBp) + 448, 1), VM8);                           \
    KTILE(0, LASTP0, WV0);                                                    \
    KTILE(1, LASTP1, WV1);                                                    \
  } while (0)

// epilogue: scale-free (norm folded into inputs), R1-proven scalar layout.
// nt stores keep the 268 MB C stream from evicting the A panel in L2.
#define EPILOGUE(col0_)                                                       \
  do {                                                                        \
    _Pragma("unroll")                                                         \
    for (int m = 0; m < 8; ++m) {                                             \
      const size_t rbase = rowA0 + wm * 128 + m * 16 + cq * 4;                \
      _Pragma("unroll")                                                       \
      for (int r = 0; r < 4; ++r) {                                           \
        float* crow = C + (rbase + r) * (size_t)M + (col0_) + wn * 64 + cc;   \
        _Pragma("unroll")                                                     \
        for (int n = 0; n < 4; ++n)                                           \
          __builtin_nontemporal_store(acc[m][n][r], crow + n * 16);           \
      }                                                                       \
    }                                                                         \
  } while (0)

__global__ __launch_bounds__(512, 2) void gemm256_kernel(
    const __hip_bfloat16* __restrict__ Abf, const __hip_bfloat16* __restrict__ Bbf,
    float* __restrict__ C, int N, int M) {
  // [ A: buf0{h0,h1} buf1{h0,h1} | B: same ] = 128 KiB (proven footprint)
  __shared__ __align__(128) short smem[65536];

  const int t    = threadIdx.x;            // 0..511
  const int lane = t & 63;
  const int w    = t >> 6;                 // 0..7
  const int wm   = w >> 2;                 // 0..1  (M half)
  const int wn   = w & 3;                  // 0..3  (N quarter)

  const int nbx = N / BM;                  // A-tiles
  const int nwg = (int)gridDim.x;
  int lb = (int)blockIdx.x;
  if ((nwg & 7) == 0) lb = (lb & 7) * (nwg >> 3) + (lb >> 3);  // XCD chunking
  const int ix  = lb % nbx;
  const int iyg = lb / nbx;                // B tile-group

  const size_t rowA0  = (size_t)ix * BM;
  const size_t rowB00 = (size_t)iyg * (BN * TPB);
  const unsigned short* gA  = (const unsigned short*)Abf + rowA0 * D;
  const unsigned short* gB0 = (const unsigned short*)Bbf + rowB00 * D;

  const int srow  = t >> 3;                       // staging row 0..63
  const int sslot = (t & 7) ^ (srow & 7);         // pre-swizzled source slot
  const size_t soff = (size_t)srow * D + sslot * 8;

  const int fr    = lane & 15;
  const int g4    = lane >> 4;
  const int rbyte = fr * 128;
  const int off0  = ((g4    ) ^ (fr & 7)) * 16;
  const int off1  = ((g4 + 4) ^ (fr & 7)) * 16;
  const int cq    = lane >> 4;
  const int cc    = lane & 15;

  floatx4 acc[8][4];
  short8 aR[4][2], bR[4][2];

  // prologue (once per block): kt0 -> buf0, kt1 -> buf1
  STAGE(gA,      gB0,      0);
  STAGE(gA + 64, gB0 + 64, 1);
  VM8;                                      // kt0 landed
  BAR;

  const unsigned short* bB = gB0;
  #pragma unroll 1
  for (int tt = 0; tt < TPB - 1; ++tt) {
    #pragma unroll
    for (int i = 0; i < 8; ++i)
      #pragma unroll
      for (int j = 0; j < 4; ++j) acc[i][j] = (floatx4){0.f, 0.f, 0.f, 0.f};

    const unsigned short* bBN = bB + BN * D;       // next tile's B base
    // kt2..kt7 of this tile, then seamlessly stage next tile's kt0'/kt1'
    TILE8(bB, STAGE(gA, bBN, 0), STAGE(gA + 64, bBN + 64, 1), VM8, VM8);
    EPILOGUE(rowB00 + (size_t)tt * BN);     // stores overlap kt0'/kt1'
    bB = bBN;
  }

  // final tile: no further staging; VM0 drains before buf reads
  #pragma unroll
  for (int i = 0; i < 8; ++i)
    #pragma unroll
    for (int j = 0; j < 4; ++j) acc[i][j] = (floatx4){0.f, 0.f, 0.f, 0.f};
  TILE8(bB, NOOP, NOOP, VM0, NOOP);
  EPILOGUE(rowB00 + (size_t)(TPB - 1) * BN);
}

// ---------------- correctness fallback (fp32, used only if !fast) ----------
__global__ __launch_bounds__(256) void fb_gemm(
    const float* __restrict__ A, const float* __restrict__ B,
    const float* __restrict__ ia, const float* __restrict__ ib,
    const int* __restrict__ nrmflag, float* __restrict__ C, int N, int M) {
  __shared__ float sA[32][33];
  __shared__ float sB[32][33];
  const int tx = threadIdx.x & 31;
  const int ty = threadIdx.x >> 5;   // 0..7
  const size_t row0 = (size_t)blockIdx.y * 32;
  const size_t col0 = (size_t)blockIdx.x * 32;
  float acc[4] = {0.f, 0.f, 0.f, 0.f};
  for (int k0 = 0; k0 < D; k0 += 32) {
    #pragma unroll
    for (int r = 0; r < 4; ++r) {
      sA[ty + 8 * r][tx] = A[(row0 + ty + 8 * r) * D + k0 + tx];
      sB[ty + 8 * r][tx] = B[(col0 + ty + 8 * r) * D + k0 + tx];
    }
    __syncthreads();
    #pragma unroll 8
    for (int kk = 0; kk < 32; ++kk) {
      const float bv = sB[tx][kk];
      #pragma unroll
      for (int r = 0; r < 4; ++r) acc[r] += sA[ty + 8 * r][kk] * bv;
    }
    __syncthreads();
  }
  const int nrm  = *nrmflag;
  const float iv = ib[col0 + tx];
  #pragma unroll
  for (int r = 0; r < 4; ++r) {
    const size_t row = row0 + ty + 8 * r;
    float v = acc[r];
    if (nrm) {
      const float denom = 1.0f / (ia[row] * iv) + EPS;  // sqrt(n1*n2)+eps
      v /= denom;
    }
    C[row * (size_t)M + col0 + tx] = v;
  }
}

extern "C" void kernel_launch(void* const* d_in, const int* in_sizes, int n_in,
                              void* d_out, int out_size, void* d_ws, size_t ws_size,
                              hipStream_t stream) {
  const float* A   = (const float*)d_in[0];
  const float* B   = (const float*)d_in[1];
  const int*   nrm = (const int*)d_in[2];
  float*       C   = (float*)d_out;
  const int N = in_sizes[0] / D;
  const int M = in_sizes[1] / D;

  // workspace layout: [ iaN (N f32) | ibN (M f32) | A_bf16 (N*D) | B_bf16 (M*D) ]
  float* iaN = (float*)d_ws;
  float* ibN = iaN + N;
  __hip_bfloat16* Abf = (__hip_bfloat16*)(ibN + M);
  __hip_bfloat16* Bbf = Abf + (size_t)N * D;

  const size_t need = (size_t)(N + M) * sizeof(float)
                    + (size_t)(N + M) * D * sizeof(__hip_bfloat16);
  const bool fast = (ws_size >= need) && (N % BM == 0) && (M % (BN * TPB) == 0);

  prep_kernel<<<(N + 3) / 4, 256, 0, stream>>>(A, fast ? Abf : nullptr, iaN, nrm, N);
  prep_kernel<<<(M + 3) / 4, 256, 0, stream>>>(B, fast ? Bbf : nullptr, ibN, nrm, M);

  if (fast) {
    const int nwg = (N / BM) * (M / (BN * TPB));   // 8192^2 -> 256 blocks
    gemm256_kernel<<<dim3(nwg), 512, 0, stream>>>(Abf, Bbf, C, N, M);
  } else {
    fb_gemm<<<dim3(M / 32, N / 32), 256, 0, stream>>>(A, B, iaN, ibN, nrm, C, N, M);
  }
}

// Round 7
// 338.289 us; speedup vs baseline: 1.1505x; 1.1505x over previous
//
#include <hip/hip_runtime.h>
#include <hip/hip_bf16.h>
#include <math.h>

#define EPS 1e-6f

constexpr int D  = 512;
constexpr int BM = 128;
constexpr int BN = 128;

typedef __attribute__((ext_vector_type(8))) short  short8;
typedef __attribute__((ext_vector_type(4))) float  floatx4;

__device__ inline unsigned short f2bf(float f) {
  union { __hip_bfloat16 h; unsigned short u; } cvt;
  cvt.h = __float2bfloat16(f);
  return cvt.u;
}

// ---------------- prep: fp32 -> bf16 (norm-folded) + ||x||^(-1/2) ----------
// HW-validated in R6 (passed, absmax 0.03125). If *nrmflag, rows are
// pre-scaled by ||row||^(-1/2) before the bf16 cast, so the GEMM epilogue is
// scale-free: a'.b' = a.b / sqrt(|a||b|). (EPS shifts the reference
// denominator by ~4e-8 relative — far below tolerance.)
__global__ __launch_bounds__(256) void prep_kernel(
    const float* __restrict__ src, __hip_bfloat16* __restrict__ dst,
    float* __restrict__ isn, const int* __restrict__ nrmflag, int nrows) {
  const int lane = threadIdx.x & 63;
  const int row  = blockIdx.x * 4 + (threadIdx.x >> 6);
  if (row >= nrows) return;

  const float4* p4 = (const float4*)(src + (size_t)row * D);
  const float4 v1 = p4[lane];
  const float4 v2 = p4[lane + 64];

  float ss = v1.x * v1.x + v1.y * v1.y + v1.z * v1.z + v1.w * v1.w
           + v2.x * v2.x + v2.y * v2.y + v2.z * v2.z + v2.w * v2.w;
  #pragma unroll
  for (int o = 32; o > 0; o >>= 1) ss += __shfl_xor(ss, o);   // all lanes get ss

  const float s4 = rsqrtf(sqrtf(ss));        // ss^(-1/4) = ||row||^(-1/2)
  if (lane == 0) isn[row] = s4;              // kept for fallback path

  if (dst != nullptr) {
    const float s = (*nrmflag) ? s4 : 1.0f;
    ushort4 u1, u2;
    u1.x = f2bf(v1.x * s); u1.y = f2bf(v1.y * s);
    u1.z = f2bf(v1.z * s); u1.w = f2bf(v1.w * s);
    u2.x = f2bf(v2.x * s); u2.y = f2bf(v2.y * s);
    u2.z = f2bf(v2.z * s); u2.w = f2bf(v2.w * s);
    ushort4* drow = (ushort4*)(dst + (size_t)row * D);
    drow[lane]      = u1;
    drow[lane + 64] = u2;
  }
}

// ---------------- main bf16 MFMA GEMM, C = A * B^T (R0 K-loop, unchanged) --
// 128x128 block tile, 32 KiB LDS -> ~3 blocks/CU (cross-block latency hiding,
// the R0 property that beat all deep-pipelined 1-block/CU variants at K=512).
// NEW vs R0:
//  (a) XCD band swizzle: XCD x owns A-tile rows [x*8, x*8+8); within an XCD,
//      consecutive local ids walk the 8 A-rows fastest -> concurrent working
//      set ~1 MB A + ~2 MB B fits the 4 MiB per-XCD L2, so panel staging is
//      L2-served instead of LLC-served (R0 had no swizzle: 16 MB/XCD set).
//  (b) scale-free epilogue (norms folded into inputs by prep) with
//      non-temporal C stores (268 MB stream must not evict L2 panels).
__global__ __launch_bounds__(256) void gemm_bt_kernel(
    const __hip_bfloat16* __restrict__ A, const __hip_bfloat16* __restrict__ B,
    float* __restrict__ C, int N, int M) {
  __shared__ __align__(16) __hip_bfloat16 sA[2][BM * 32];   // 16 KiB
  __shared__ __align__(16) __hip_bfloat16 sB[2][BN * 32];   // 16 KiB

  const int t    = threadIdx.x;
  const int w    = t >> 6;
  const int lane = t & 63;
  const int wm   = w & 1;        // wave row (0..1)
  const int wn   = w >> 1;       // wave col (0..1)

  // (a) XCD band swizzle (bijective; requires gridDim.x % 8 == 0)
  size_t rowA0, rowB0;
  {
    const int gx   = (int)gridDim.x;
    const int orig = (int)(blockIdx.y * gridDim.x + blockIdx.x);
    if ((gx & 7) == 0) {
      const int bandw = gx >> 3;           // A-rows per XCD band
      const int xcd = orig & 7;            // HW round-robins wg->XCD by id
      const int loc = orig >> 3;
      const int ir  = xcd * bandw + (loc % bandw);
      const int ic  = loc / bandw;
      rowA0 = (size_t)ir * BM;
      rowB0 = (size_t)ic * BN;
    } else {
      rowA0 = (size_t)blockIdx.x * BM;
      rowB0 = (size_t)blockIdx.y * BN;
    }
  }

  floatx4 acc[4][4];
  #pragma unroll
  for (int i = 0; i < 4; ++i)
    #pragma unroll
    for (int j = 0; j < 4; ++j) acc[i][j] = (floatx4){0.f, 0.f, 0.f, 0.f};

  // staging: one wave instr = 1 KiB = 16 rows x 64B. lane -> row lane/4,
  // 16B piece (lane%4) of the 64B (=32 bf16) row chunk.
  const int ldRow = lane >> 2;           // 0..15
  const int ldCol = (lane & 3) * 8;      // bf16: 0,8,16,24
  // fragment geometry: A[m=lane&15][k=(lane>>4)*8 + j]
  const int fr = lane & 15;
  const int fq = (lane >> 4) * 8;

  const __hip_bfloat16* gA0 = A + (rowA0 + (size_t)ldRow) * D + ldCol;
  const __hip_bfloat16* gB0 = B + (rowB0 + (size_t)ldRow) * D + ldCol;

  for (int k0 = 0; k0 < D; k0 += 64) {
    #pragma unroll
    for (int h = 0; h < 2; ++h) {
      const int kc = k0 + h * 32;
      #pragma unroll
      for (int j = 0; j < 2; ++j) {
        const int c = w * 2 + j;           // chunk 0..7, wave-uniform
        __builtin_amdgcn_global_load_lds(
            (const __attribute__((address_space(1))) void*)(gA0 + (size_t)(c * 16) * D + kc),
            (__attribute__((address_space(3))) void*)(&sA[h][c * 512]), 16, 0, 0);
        __builtin_amdgcn_global_load_lds(
            (const __attribute__((address_space(1))) void*)(gB0 + (size_t)(c * 16) * D + kc),
            (__attribute__((address_space(3))) void*)(&sB[h][c * 512]), 16, 0, 0);
      }
    }
    __syncthreads();   // drains vmcnt(0): both k-half tiles visible

    #pragma unroll
    for (int h = 0; h < 2; ++h) {
      short8 af[4], bf[4];
      #pragma unroll
      for (int i = 0; i < 4; ++i) {
        af[i] = *(const short8*)(&sA[h][(wm * 64 + i * 16 + fr) * 32 + fq]);
        bf[i] = *(const short8*)(&sB[h][(wn * 64 + i * 16 + fr) * 32 + fq]);
      }
      #pragma unroll
      for (int i = 0; i < 4; ++i)
        #pragma unroll
        for (int j = 0; j < 4; ++j)
          acc[i][j] = __builtin_amdgcn_mfma_f32_16x16x32_bf16(af[i], bf[j], acc[i][j], 0, 0, 0);
    }
    __syncthreads();
  }

  // (b) epilogue: scale-free, nt stores.
  // C/D layout col=lane&15, row=(lane>>4)*4+reg  [m89/m91-verified]
  const int cq = lane >> 4;   // 0..3
  const int cc = lane & 15;

  #pragma unroll
  for (int i = 0; i < 4; ++i) {
    const size_t rbase = rowA0 + wm * 64 + i * 16 + cq * 4;
    #pragma unroll
    for (int r = 0; r < 4; ++r) {
      float* crow = C + (rbase + r) * (size_t)M + rowB0 + wn * 64 + cc;
      #pragma unroll
      for (int j = 0; j < 4; ++j)
        __builtin_nontemporal_store(acc[i][j][r], crow + j * 16);
    }
  }
}

// ---------------- correctness fallback (fp32, used only if !fast) ----------
__global__ __launch_bounds__(256) void fb_gemm(
    const float* __restrict__ A, const float* __restrict__ B,
    const float* __restrict__ ia, const float* __restrict__ ib,
    const int* __restrict__ nrmflag, float* __restrict__ C, int N, int M) {
  __shared__ float sA[32][33];
  __shared__ float sB[32][33];
  const int tx = threadIdx.x & 31;
  const int ty = threadIdx.x >> 5;   // 0..7
  const size_t row0 = (size_t)blockIdx.y * 32;
  const size_t col0 = (size_t)blockIdx.x * 32;
  float acc[4] = {0.f, 0.f, 0.f, 0.f};
  for (int k0 = 0; k0 < D; k0 += 32) {
    #pragma unroll
    for (int r = 0; r < 4; ++r) {
      sA[ty + 8 * r][tx] = A[(row0 + ty + 8 * r) * D + k0 + tx];
      sB[ty + 8 * r][tx] = B[(col0 + ty + 8 * r) * D + k0 + tx];
    }
    __syncthreads();
    #pragma unroll 8
    for (int kk = 0; kk < 32; ++kk) {
      const float bv = sB[tx][kk];
      #pragma unroll
      for (int r = 0; r < 4; ++r) acc[r] += sA[ty + 8 * r][kk] * bv;
    }
    __syncthreads();
  }
  const int nrm  = *nrmflag;
  const float iv = ib[col0 + tx];
  #pragma unroll
  for (int r = 0; r < 4; ++r) {
    const size_t row = row0 + ty + 8 * r;
    float v = acc[r];
    if (nrm) {
      const float denom = 1.0f / (ia[row] * iv) + EPS;  // sqrt(n1*n2)+eps
      v /= denom;
    }
    C[row * (size_t)M + col0 + tx] = v;
  }
}

extern "C" void kernel_launch(void* const* d_in, const int* in_sizes, int n_in,
                              void* d_out, int out_size, void* d_ws, size_t ws_size,
                              hipStream_t stream) {
  const float* A   = (const float*)d_in[0];
  const float* B   = (const float*)d_in[1];
  const int*   nrm = (const int*)d_in[2];
  float*       C   = (float*)d_out;
  const int N = in_sizes[0] / D;
  const int M = in_sizes[1] / D;

  // workspace layout: [ iaN (N f32) | ibN (M f32) | A_bf16 (N*D) | B_bf16 (M*D) ]
  float* iaN = (float*)d_ws;
  float* ibN = iaN + N;
  __hip_bfloat16* Abf = (__hip_bfloat16*)(ibN + M);
  __hip_bfloat16* Bbf = Abf + (size_t)N * D;

  const size_t need = (size_t)(N + M) * sizeof(float)
                    + (size_t)(N + M) * D * sizeof(__hip_bfloat16);
  const bool fast = (ws_size >= need) && (N % BM == 0) && (M % BN == 0);

  prep_kernel<<<(N + 3) / 4, 256, 0, stream>>>(A, fast ? Abf : nullptr, iaN, nrm, N);
  prep_kernel<<<(M + 3) / 4, 256, 0, stream>>>(B, fast ? Bbf : nullptr, ibN, nrm, M);

  if (fast) {
    gemm_bt_kernel<<<dim3(N / BM, M / BN), 256, 0, stream>>>(Abf, Bbf, C, N, M);
  } else {
    fb_gemm<<<dim3(M / 32, N / 32), 256, 0, stream>>>(A, B, iaN, ibN, nrm, C, N, M);
  }
}